// Round 3
// baseline (109.182 us; speedup 1.0000x reference)
//
#include <hip/hip_runtime.h>
#include <math.h>

#define Dd 96
#define Nn 48
#define LD 97
#define PTS 98   // even stride: keeps float2 (8 B) LDS loads aligned

// Fast full-precision f64 reciprocal: v_rcp_f64 + 2 Newton steps (<=1 ulp).
__device__ __forceinline__ double frcp(double x) {
    double r = __builtin_amdgcn_rcp(x);
    r = fma(fma(-x, r, 1.0), r, r);
    r = fma(fma(-x, r, 1.0), r, r);
    return r;
}

// One block per particle k (P f32; R16-verified math).
// R22: throughput attack.
//  - 1024 threads (16 waves, 4/SIMD): 2x latency-hiding pool, rows/wave /2.
//  - S-trick: per lane, once per step, solve B*S = R (panel inverse folded
//    into the R-rows; S = B^-1 R at this lane's two col slots). Row update
//    becomes T -= a0*S0+a1*S1+a2*S2+a3*S3 -- no per-row multiplier chain,
//    no back-substitution: VALU in the dominant loop /2.5, chain 15->4.
//    Algebraically identical (w = B^-T a  <=>  update -= a^T B^-1 R).
//  - guards/emission semantics identical to R16; merged prod epilogue kept.
__global__ __launch_bounds__(1024, 1) void slater_kernel(const float* __restrict__ P,
                                                         const int* __restrict__ occ,
                                                         float* __restrict__ out,
                                                         unsigned* __restrict__ cnt) {
    __shared__ double As[Dd * LD];      // 74,496 B
    __shared__ unsigned char flag[Dd];
    float* PT = (float*)As;             // scratch alias; PT reads end before As writes

    const int tid  = threadIdx.x;
    const int k    = blockIdx.x;
    const int n    = Dd - Nn + k + 1;   // xmax
    const int lane = tid & 63;
    const int wave = tid >> 6;          // 0..15
    const int xmin = (k == 0) ? 0 : occ[k - 1] + 1;

    if (tid < Dd) flag[tid] = 0;
    __syncthreads();
    if (tid < k) flag[occ[tid]] = 1;
    for (int e = tid; e < Dd * Nn; e += 1024) {      // PT[t][c] = P[c][t]
        int c = e / Nn, t = e - (e / Nn) * Nn;
        PT[t * PTS + c] = P[e];
    }
    __syncthreads();

    // A = I*(1-flag) - P P^T is SYMMETRIC: upper-tri 2x2 tiles (1176), mirror
    // writes for the lower half. 1024 threads -> 2 partial iterations.
    double Areg[8]; int trs[2], tcs[2];
#pragma unroll
    for (int it = 0; it < 2; ++it) {
        int tau = tid + 1024 * it;
        double s00 = 0.0, s01 = 0.0, s10 = 0.0, s11 = 0.0;
        int tr = 0, tc = 0;
        if (tau < 1176) {
            tr = (int)((97.0 - sqrt(9409.0 - 8.0 * (double)tau)) * 0.5);
            while ((tr * (97 - tr)) / 2 > tau) --tr;            // off(tr) <= tau
            while (((tr + 1) * (96 - tr)) / 2 <= tau) ++tr;     // off(tr+1) > tau
            tc = tr + (tau - (tr * (97 - tr)) / 2);
            int r0 = 2 * tr, c0 = 2 * tc;
            if (r0 < n && c0 < n) {
                for (int t = 0; t < Nn; ++t) {
                    const float* row = PT + t * PTS;
                    float2 pr = *(const float2*)(row + r0);
                    float2 pc = *(const float2*)(row + c0);
                    s00 -= (double)pr.x * (double)pc.x; s01 -= (double)pr.x * (double)pc.y;
                    s10 -= (double)pr.y * (double)pc.x; s11 -= (double)pr.y * (double)pc.y;
                }
            }
        }
        trs[it] = tr; tcs[it] = tc;
        Areg[it * 4 + 0] = s00; Areg[it * 4 + 1] = s01;
        Areg[it * 4 + 2] = s10; Areg[it * 4 + 3] = s11;
    }
    __syncthreads();                    // all PT reads done before As overwrite
#pragma unroll
    for (int it = 0; it < 2; ++it) {
        int tau = tid + 1024 * it;
        if (tau < 1176) {
            int tr = trs[it], tc = tcs[it];
            int r0 = 2 * tr, c0 = 2 * tc;
            if (r0 < n && c0 < n) {
                bool r1 = (r0 + 1 < n), c1 = (c0 + 1 < n);
                double d0 = flag[r0] ? 0.0 : 1.0;
                double d1 = flag[r0 + 1] ? 0.0 : 1.0;
                As[r0 * LD + c0] = Areg[it * 4 + 0] + ((r0 == c0) ? d0 : 0.0);
                if (c1)       As[r0 * LD + c0 + 1]       = Areg[it * 4 + 1];
                if (r1)       As[(r0 + 1) * LD + c0]     = Areg[it * 4 + 2];
                if (r1 && c1) As[(r0 + 1) * LD + c0 + 1] = Areg[it * 4 + 3] + ((r0 == c0) ? d1 : 0.0);
                if (tr != tc) {  // mirror (transpose) write
                    As[c0 * LD + r0] = Areg[it * 4 + 0];
                    if (c1)       As[(c0 + 1) * LD + r0]     = Areg[it * 4 + 1];
                    if (r1)       As[c0 * LD + r0 + 1]       = Areg[it * 4 + 2];
                    if (r1 && c1) As[(c0 + 1) * LD + r0 + 1] = Areg[it * 4 + 3];
                }
            }
        }
    }
    __syncthreads();

    double runprod = 1.0;
    double myprob  = 0.0;
    bool   dead    = false;            // block-uniform

    // Guard/emission, identical semantics to R16 (emit BEFORE any cut).
    auto guard = [&](int jj, double pivot) {
        double ap = fabs(pivot);
        if (jj >= xmin) {
            if (tid == jj) myprob = runprod * (1.0 - pivot);
            double newrun = runprod * pivot;
            if (!(ap > 1e-7) || !(ap < 8.0) || !(fabs(newrun) > 1e-8)) dead = true;
            else runprod = newrun;
        } else {
            if (!(ap > 1e-12) || !(ap < 8.0)) dead = true;
        }
    };

    int j = 0;
    // ---- rank-4 super-steps: eliminate cols j..j+3 (all pivots interior) ----
    for (; !dead && j + 4 <= n - 1; j += 4) {
        // ALL reads first (clamped addrs, unconditional): latency flies under
        // the register LU chain. dead==false here by loop guard.
        int t = n - (j + 4);
        bool ok0 = (lane < t), ok1 = (lane + 64 < t);
        int c0 = j + 4 + (ok0 ? lane : 0);
        int c1 = j + 4 + (ok1 ? lane + 64 : 0);
        double R0c0 = As[j * LD + c0],       R1c0 = As[(j + 1) * LD + c0];
        double R2c0 = As[(j + 2) * LD + c0], R3c0 = As[(j + 3) * LD + c0];
        double R0c1 = As[j * LD + c1],       R1c1 = As[(j + 1) * LD + c1];
        double R2c1 = As[(j + 2) * LD + c1], R3c1 = As[(j + 3) * LD + c1];

        const double* Bp0 = As + j * LD + j;
        const double* Bp1 = Bp0 + LD;
        const double* Bp2 = Bp1 + LD;
        const double* Bp3 = Bp2 + LD;
        double B00 = Bp0[0], B01 = Bp0[1], B02 = Bp0[2], B03 = Bp0[3];
        double B10 = Bp1[0], B11 = Bp1[1], B12 = Bp1[2], B13 = Bp1[3];
        double B20 = Bp2[0], B21 = Bp2[1], B22 = Bp2[2], B23 = Bp2[3];
        double B30 = Bp3[0], B31 = Bp3[1], B32 = Bp3[2], B33 = Bp3[3];

        // 4x4 panel LU in registers, redundantly in every thread.
        double piv0 = B00;
        double rp0  = frcp(piv0);
        double m10  = B10 * rp0;
        double u01 = B01, u02 = B02, u03 = B03;
        double piv1 = B11 - m10 * u01;
        double u12  = B12 - m10 * u02;
        double u13  = B13 - m10 * u03;
        double rp1  = frcp(piv1);
        double m20  = B20 * rp0;
        double m21  = (B21 - m20 * u01) * rp1;
        double piv2 = B22 - m20 * u02 - m21 * u12;
        double u23  = B23 - m20 * u03 - m21 * u13;
        double rp2  = frcp(piv2);
        double m30  = B30 * rp0;
        double m31  = (B31 - m30 * u01) * rp1;
        double m32  = (B32 - m30 * u02 - m31 * u12) * rp2;
        double piv3 = B33 - m30 * u03 - m31 * u13 - m32 * u23;
        double rp3  = frcp(piv3);

        guard(j + 0, piv0);
        if (!dead) guard(j + 1, piv1);
        if (!dead) guard(j + 2, piv2);
        if (!dead) guard(j + 3, piv3);

        if (!dead) {
            // S = B^-1 R at this lane's two col slots (L-solve then U-solve).
            double y0 = R0c0;
            double y1 = R1c0 - m10 * y0;
            double y2 = R2c0 - m20 * y0 - m21 * y1;
            double y3 = R3c0 - m30 * y0 - m31 * y1 - m32 * y2;
            double s3c0 = y3 * rp3;
            double s2c0 = (y2 - u23 * s3c0) * rp2;
            double s1c0 = (y1 - u12 * s2c0 - u13 * s3c0) * rp1;
            double s0c0 = (y0 - u01 * s1c0 - u02 * s2c0 - u03 * s3c0) * rp0;
            double z0 = R0c1;
            double z1 = R1c1 - m10 * z0;
            double z2 = R2c1 - m20 * z0 - m21 * z1;
            double z3 = R3c1 - m30 * z0 - m31 * z1 - m32 * z2;
            double s3c1 = z3 * rp3;
            double s2c1 = (z2 - u23 * s3c1) * rp2;
            double s1c1 = (z1 - u12 * s2c1 - u13 * s3c1) * rp1;
            double s0c1 = (z0 - u01 * s1c1 - u02 * s2c1 - u03 * s3c1) * rp0;

            // 4-row unrolled update: all loads in flight before any math.
            for (int i = j + 4 + wave; i < n; i += 64) {
                double a0[4], a1[4], a2[4], a3[4], T0[4], T1[4];
                bool h[4];
#pragma unroll
                for (int u = 0; u < 4; ++u) {
                    int r = i + u * 16;
                    h[u] = (r < n);
                    const double* rw = As + (h[u] ? r : i) * LD;
                    a0[u] = rw[j];     a1[u] = rw[j + 1];
                    a2[u] = rw[j + 2]; a3[u] = rw[j + 3];
                    T0[u] = rw[c0];    T1[u] = rw[c1];
                }
#pragma unroll
                for (int u = 0; u < 4; ++u) {
                    if (h[u]) {
                        double* rw = As + (i + u * 16) * LD;
                        if (ok0) rw[c0] = T0[u] - a0[u] * s0c0 - a1[u] * s1c0
                                                - a2[u] * s2c0 - a3[u] * s3c0;
                        if (ok1) rw[c1] = T1[u] - a0[u] * s0c1 - a1[u] * s1c1
                                                - a2[u] * s2c1 - a3[u] * s3c1;
                    }
                }
            }
        }
        __syncthreads();
    }

    // ---- remainder single steps (R16-proven body, 16-wave stride) ----
    for (; !dead && j < n - 1; ++j) {
        double pivot = As[j * LD + j];
        guard(j, pivot);
        if (dead) break;
        double rp = frcp(pivot);
        int t = n - 1 - j;
        double r0 = (lane < t)      ? As[j * LD + j + 1 + lane]  : 0.0;
        double r1 = (lane + 64 < t) ? As[j * LD + j + 65 + lane] : 0.0;
        for (int i = j + 1 + wave; i < n; i += 16) {
            double mult = As[i * LD + j] * rp;
            if (lane < t)      As[i * LD + j + 1 + lane]  -= mult * r0;
            if (lane + 64 < t) As[i * LD + j + 65 + lane] -= mult * r1;
        }
        __syncthreads();
    }
    if (!dead && tid == n - 1) {        // x = xmax-1: remaining mass
        double pl = As[(n - 1) * LD + (n - 1)];
        myprob = runprod * (1.0 - pl);
    }

    if (tid < Dd) {
        double p = myprob;
        if (!isfinite(p)) p = 0.0;
        if (!(fabs(p) > 1e-15)) p = 0.0;   // reference's flush
        p = fmin(fmax(p, 0.0), 1.0);       // junk-proof projection
        out[k * Dd + tid] = (float)p;
    }

    // ---- merged prob_sample: last-arriving block does the product ----
    __threadfence();
    __syncthreads();
    if (wave == 0) {
        int old = 0;
        if (lane == 0)
            old = (int)__hip_atomic_fetch_add(cnt, 1u, __ATOMIC_ACQ_REL,
                                              __HIP_MEMORY_SCOPE_AGENT);
        old = __shfl(old, 0, 64);
        // Exactly one multiple of Nn in any Nn consecutive values -> exactly
        // one trigger per launch for ANY initial/poisoned counter value.
        if (((unsigned)old + 1u) % (unsigned)Nn == 0u) {
            __threadfence();            // acquire side
            double v = 1.0;
            if (lane < Nn) {
                float f = __hip_atomic_load(out + lane * Dd + occ[lane],
                                            __ATOMIC_RELAXED, __HIP_MEMORY_SCOPE_AGENT);
                v = (double)f;
            }
#pragma unroll
            for (int off = 32; off >= 1; off >>= 1)
                v *= __shfl_down(v, off, 64);
            if (lane == 0) {
                if (!isfinite(v)) v = 0.0;
                out[Nn * Dd] = (float)v;
            }
        }
    }
}

extern "C" void kernel_launch(void* const* d_in, const int* in_sizes, int n_in,
                              void* d_out, int out_size, void* d_ws, size_t ws_size,
                              hipStream_t stream) {
    const float* P = (const float*)d_in[0];      // 96x48 f32, row-major
    const int* occ = (const int*)d_in[1];        // 48 int32
    float* out = (float*)d_out;                  // 4609 f32

    slater_kernel<<<Nn, 1024, 0, stream>>>(P, occ, out, (unsigned*)d_ws);
}

// Round 4
// 105.814 us; speedup vs baseline: 1.0318x; 1.0318x over previous
//
#include <hip/hip_runtime.h>
#include <math.h>

#define Dd 96
#define Nn 48
#define LD 97
#define PTS 98   // even stride: keeps float2 (8 B) LDS loads aligned

// Fast full-precision f64 reciprocal: v_rcp_f64 + 2 Newton steps (<=1 ulp).
__device__ __forceinline__ double frcp(double x) {
    double r = __builtin_amdgcn_rcp(x);
    r = fma(fma(-x, r, 1.0), r, r);
    r = fma(fma(-x, r, 1.0), r, r);
    return r;
}

// One block per particle k (P f32; R16-verified math).
// R23: dedupe the replicated per-step work (R19≈R21≈R22 plateau diagnosis:
// per-step cost dominated by panel LU + guards replicated in EVERY wave).
//  - Panel LU + guard chain run ONCE (wave15 lane0) with LOOKAHEAD: during
//    step j's update, waves 0-3 update rows j+4..j+7 first and signal an LDS
//    counter; wave15 spins, factors panel j+4, runs guards for the next step,
//    stores factors/emission-values/dead-flag to a parity double buffer.
//    Factor chain (~700cy) hides under the 14 update waves. 1 barrier/step.
//  - Step-top per thread: read broadcast factors + 1 dead flag; 4 threads
//    pick up their precomputed emission value. Bit-identical math to R22.
//  - Counter is monotonic (target 4,8,12,...) -> no reset, no memset needed.
__global__ __launch_bounds__(1024, 1) void slater_kernel(const float* __restrict__ P,
                                                         const int* __restrict__ occ,
                                                         float* __restrict__ out,
                                                         unsigned* __restrict__ cnt) {
    __shared__ double As[Dd * LD];      // 74,496 B
    __shared__ double fac[2][16];       // m10,m20,m21,m30,m31,m32,u01,u02,u03,u12,u13,u23,rp0..rp3
    __shared__ double ev[2][4];         // emission values for the step's 4 pivots
    __shared__ int    evmask[2];
    __shared__ int    sdead[2];
    __shared__ double gs_runprod;       // guard-state handoff for remainder steps
    __shared__ int    gs_dead;
    __shared__ int    rdy;              // monotonic priority-row arrival counter
    __shared__ unsigned char flag[Dd];
    float* PT = (float*)As;             // scratch alias; PT reads end before As writes

    const int tid  = threadIdx.x;
    const int k    = blockIdx.x;
    const int n    = Dd - Nn + k + 1;   // xmax
    const int lane = tid & 63;
    const int wave = tid >> 6;          // 0..15
    const int xmin = (k == 0) ? 0 : occ[k - 1] + 1;

    if (tid == 0) rdy = 0;
    if (tid < Dd) flag[tid] = 0;
    __syncthreads();
    if (tid < k) flag[occ[tid]] = 1;
    for (int e = tid; e < Dd * Nn; e += 1024) {      // PT[t][c] = P[c][t]
        int c = e / Nn, t = e - (e / Nn) * Nn;
        PT[t * PTS + c] = P[e];
    }
    __syncthreads();

    // A = I*(1-flag) - P P^T is SYMMETRIC: upper-tri 2x2 tiles (1176), mirror
    // writes for the lower half. 1024 threads -> 2 partial iterations.
    double Areg[8]; int trs[2], tcs[2];
#pragma unroll
    for (int it = 0; it < 2; ++it) {
        int tau = tid + 1024 * it;
        double s00 = 0.0, s01 = 0.0, s10 = 0.0, s11 = 0.0;
        int tr = 0, tc = 0;
        if (tau < 1176) {
            tr = (int)((97.0 - sqrt(9409.0 - 8.0 * (double)tau)) * 0.5);
            while ((tr * (97 - tr)) / 2 > tau) --tr;            // off(tr) <= tau
            while (((tr + 1) * (96 - tr)) / 2 <= tau) ++tr;     // off(tr+1) > tau
            tc = tr + (tau - (tr * (97 - tr)) / 2);
            int r0 = 2 * tr, c0 = 2 * tc;
            if (r0 < n && c0 < n) {
                for (int t = 0; t < Nn; ++t) {
                    const float* row = PT + t * PTS;
                    float2 pr = *(const float2*)(row + r0);
                    float2 pc = *(const float2*)(row + c0);
                    s00 -= (double)pr.x * (double)pc.x; s01 -= (double)pr.x * (double)pc.y;
                    s10 -= (double)pr.y * (double)pc.x; s11 -= (double)pr.y * (double)pc.y;
                }
            }
        }
        trs[it] = tr; tcs[it] = tc;
        Areg[it * 4 + 0] = s00; Areg[it * 4 + 1] = s01;
        Areg[it * 4 + 2] = s10; Areg[it * 4 + 3] = s11;
    }
    __syncthreads();                    // all PT reads done before As overwrite
#pragma unroll
    for (int it = 0; it < 2; ++it) {
        int tau = tid + 1024 * it;
        if (tau < 1176) {
            int tr = trs[it], tc = tcs[it];
            int r0 = 2 * tr, c0 = 2 * tc;
            if (r0 < n && c0 < n) {
                bool r1 = (r0 + 1 < n), c1 = (c0 + 1 < n);
                double d0 = flag[r0] ? 0.0 : 1.0;
                double d1 = flag[r0 + 1] ? 0.0 : 1.0;
                As[r0 * LD + c0] = Areg[it * 4 + 0] + ((r0 == c0) ? d0 : 0.0);
                if (c1)       As[r0 * LD + c0 + 1]       = Areg[it * 4 + 1];
                if (r1)       As[(r0 + 1) * LD + c0]     = Areg[it * 4 + 2];
                if (r1 && c1) As[(r0 + 1) * LD + c0 + 1] = Areg[it * 4 + 3] + ((r0 == c0) ? d1 : 0.0);
                if (tr != tc) {  // mirror (transpose) write
                    As[c0 * LD + r0] = Areg[it * 4 + 0];
                    if (c1)       As[(c0 + 1) * LD + r0]     = Areg[it * 4 + 1];
                    if (r1)       As[c0 * LD + r0 + 1]       = Areg[it * 4 + 2];
                    if (r1 && c1) As[(c0 + 1) * LD + r0 + 1] = Areg[it * 4 + 3];
                }
            }
        }
    }
    __syncthreads();

    double myprob = 0.0;
    double grun = 1.0;                  // guard state (meaningful on wave15 lane0)
    int    gdead = 0;

    // Factor panel [jb..jb+3]^2 + run guard chain for its 4 pivots; store to
    // parity p. Exact same op sequence as R22's redundant per-thread version.
    auto prefactor = [&](int jb, int p) {
        const double* q0 = As + jb * LD + jb;
        const double* q1 = q0 + LD;
        const double* q2 = q1 + LD;
        const double* q3 = q2 + LD;
        double B00=q0[0],B01=q0[1],B02=q0[2],B03=q0[3];
        double B10=q1[0],B11=q1[1],B12=q1[2],B13=q1[3];
        double B20=q2[0],B21=q2[1],B22=q2[2],B23=q2[3];
        double B30=q3[0],B31=q3[1],B32=q3[2],B33=q3[3];
        double piv0=B00, rp0=frcp(piv0);
        double m10=B10*rp0;
        double u01=B01,u02=B02,u03=B03;
        double piv1=B11-m10*u01;
        double u12=B12-m10*u02, u13=B13-m10*u03;
        double rp1=frcp(piv1);
        double m20=B20*rp0;
        double m21=(B21-m20*u01)*rp1;
        double piv2=B22-m20*u02-m21*u12;
        double u23=B23-m20*u03-m21*u13;
        double rp2=frcp(piv2);
        double m30=B30*rp0;
        double m31=(B31-m30*u01)*rp1;
        double m32=(B32-m30*u02-m31*u12)*rp2;
        double piv3=B33-m30*u03-m31*u13-m32*u23;
        double rp3=frcp(piv3);
        double pivs[4]={piv0,piv1,piv2,piv3};
        double evv[4]={0.0,0.0,0.0,0.0};
        int msk=0;
#pragma unroll
        for (int q = 0; q < 4; ++q) {
            if (!gdead) {
                int jj = jb + q;
                double piv = pivs[q];
                double ap = fabs(piv);
                if (jj >= xmin) {
                    evv[q] = grun * (1.0 - piv);    // emit BEFORE any cut
                    msk |= (1 << q);
                    double nr = grun * piv;
                    if (!(ap > 1e-7) || !(ap < 8.0) || !(fabs(nr) > 1e-8)) gdead = 1;
                    else grun = nr;
                } else {
                    if (!(ap > 1e-12) || !(ap < 8.0)) gdead = 1;
                }
            }
        }
        fac[p][0]=m10; fac[p][1]=m20; fac[p][2]=m21; fac[p][3]=m30; fac[p][4]=m31; fac[p][5]=m32;
        fac[p][6]=u01; fac[p][7]=u02; fac[p][8]=u03; fac[p][9]=u12; fac[p][10]=u13; fac[p][11]=u23;
        fac[p][12]=rp0; fac[p][13]=rp1; fac[p][14]=rp2; fac[p][15]=rp3;
        ev[p][0]=evv[0]; ev[p][1]=evv[1]; ev[p][2]=evv[2]; ev[p][3]=evv[3];
        evmask[p]=msk; sdead[p]=gdead;
        gs_runprod=grun; gs_dead=gdead;
    };

    if (wave == 15 && lane == 0) prefactor(0, 0);   // step-0 factors
    __syncthreads();

    int j = 0, s = 0, target = 4;
    for (; j + 4 <= n - 1; j += 4, ++s) {
        const int par = s & 1;
        // emission for this step (values precomputed by wave15)
        if ((tid >> 2) == s) {
            int q = tid & 3;
            if ((evmask[par] >> q) & 1) myprob = ev[par][q];
        }
        if (sdead[par]) break;          // dead before this step's update
        const bool nextex = (j + 8 <= n - 1);   // next super-step exists (t>=4)

        if (wave == 15) {
            if (nextex) {
                while (__hip_atomic_load(&rdy, __ATOMIC_ACQUIRE,
                                         __HIP_MEMORY_SCOPE_WORKGROUP) < target)
                    __builtin_amdgcn_s_sleep(1);
                target += 4;
                __threadfence_block();
                if (lane == 0) prefactor(j + 4, par ^ 1);
            }
        } else {
            const int t = n - (j + 4);
            const bool ok0 = (lane < t), ok1 = (lane + 64 < t);
            const int c0 = j + 4 + (ok0 ? lane : 0);
            const int c1 = j + 4 + (ok1 ? lane + 64 : 0);
            const double m10=fac[par][0], m20=fac[par][1], m21=fac[par][2],
                         m30=fac[par][3], m31=fac[par][4], m32=fac[par][5];
            const double u01=fac[par][6], u02=fac[par][7], u03=fac[par][8],
                         u12=fac[par][9], u13=fac[par][10], u23=fac[par][11];
            const double rp0=fac[par][12], rp1=fac[par][13],
                         rp2=fac[par][14], rp3=fac[par][15];
            const double R0c0=As[j*LD+c0],     R1c0=As[(j+1)*LD+c0];
            const double R2c0=As[(j+2)*LD+c0], R3c0=As[(j+3)*LD+c0];
            const double R0c1=As[j*LD+c1],     R1c1=As[(j+1)*LD+c1];
            const double R2c1=As[(j+2)*LD+c1], R3c1=As[(j+3)*LD+c1];
            // S = B^-1 R at this lane's two col slots.
            double y0=R0c0, y1=R1c0-m10*y0, y2=R2c0-m20*y0-m21*y1,
                   y3=R3c0-m30*y0-m31*y1-m32*y2;
            double s3c0=y3*rp3, s2c0=(y2-u23*s3c0)*rp2,
                   s1c0=(y1-u12*s2c0-u13*s3c0)*rp1,
                   s0c0=(y0-u01*s1c0-u02*s2c0-u03*s3c0)*rp0;
            double z0=R0c1, z1=R1c1-m10*z0, z2=R2c1-m20*z0-m21*z1,
                   z3=R3c1-m30*z0-m31*z1-m32*z2;
            double s3c1=z3*rp3, s2c1=(z2-u23*s3c1)*rp2,
                   s1c1=(z1-u12*s2c1-u13*s3c1)*rp1,
                   s0c1=(z0-u01*s1c1-u02*s2c1-u03*s3c1)*rp0;

            // rows strided over waves 0..14; wave w's FIRST row is j+4+w, so
            // waves 0-3 complete the next panel's rows first and signal.
            int i = j + 4 + wave;
            if (i < n) {
                {
                    double* rw = As + i * LD;
                    double a0=rw[j], a1=rw[j+1], a2=rw[j+2], a3=rw[j+3];
                    double T0=rw[c0], T1=rw[c1];
                    double v0=T0 - a0*s0c0 - a1*s1c0 - a2*s2c0 - a3*s3c0;
                    double v1=T1 - a0*s0c1 - a1*s1c1 - a2*s2c1 - a3*s3c1;
                    if (ok0) rw[c0]=v0;
                    if (ok1) rw[c1]=v1;
                }
                if (wave < 4 && nextex) {
                    __threadfence_block();   // row writes visible before signal
                    if (lane == 0)
                        __hip_atomic_fetch_add(&rdy, 1, __ATOMIC_RELEASE,
                                               __HIP_MEMORY_SCOPE_WORKGROUP);
                }
                for (i += 15; i < n; i += 15) {
                    double* rw = As + i * LD;
                    double a0=rw[j], a1=rw[j+1], a2=rw[j+2], a3=rw[j+3];
                    double T0=rw[c0], T1=rw[c1];
                    double v0=T0 - a0*s0c0 - a1*s1c0 - a2*s2c0 - a3*s3c0;
                    double v1=T1 - a0*s0c1 - a1*s1c1 - a2*s2c1 - a3*s3c1;
                    if (ok0) rw[c0]=v0;
                    if (ok1) rw[c1]=v1;
                }
            }
        }
        __syncthreads();
    }

    // guard-state handoff (written by wave15's last prefactor; barrier-ordered)
    double runprod = gs_runprod;
    bool   dead    = (gs_dead != 0);

    // ---- remainder single steps (R16-proven body, 16-wave stride) ----
    for (; !dead && j < n - 1; ++j) {
        double pivot = As[j * LD + j];
        {
            double ap = fabs(pivot);
            if (j >= xmin) {
                if (tid == j) myprob = runprod * (1.0 - pivot);
                double nr = runprod * pivot;
                if (!(ap > 1e-7) || !(ap < 8.0) || !(fabs(nr) > 1e-8)) dead = true;
                else runprod = nr;
            } else {
                if (!(ap > 1e-12) || !(ap < 8.0)) dead = true;
            }
        }
        if (dead) break;
        double rp = frcp(pivot);
        int t = n - 1 - j;
        double r0 = (lane < t)      ? As[j * LD + j + 1 + lane]  : 0.0;
        double r1 = (lane + 64 < t) ? As[j * LD + j + 65 + lane] : 0.0;
        for (int i = j + 1 + wave; i < n; i += 16) {
            double mult = As[i * LD + j] * rp;
            if (lane < t)      As[i * LD + j + 1 + lane]  -= mult * r0;
            if (lane + 64 < t) As[i * LD + j + 65 + lane] -= mult * r1;
        }
        __syncthreads();
    }
    if (!dead && tid == n - 1) {        // x = xmax-1: remaining mass
        double pl = As[(n - 1) * LD + (n - 1)];
        myprob = runprod * (1.0 - pl);
    }

    if (tid < Dd) {
        double p = myprob;
        if (!isfinite(p)) p = 0.0;
        if (!(fabs(p) > 1e-15)) p = 0.0;   // reference's flush
        p = fmin(fmax(p, 0.0), 1.0);       // junk-proof projection
        out[k * Dd + tid] = (float)p;
    }

    // ---- merged prob_sample: last-arriving block does the product ----
    __threadfence();
    __syncthreads();
    if (wave == 0) {
        int old = 0;
        if (lane == 0)
            old = (int)__hip_atomic_fetch_add(cnt, 1u, __ATOMIC_ACQ_REL,
                                              __HIP_MEMORY_SCOPE_AGENT);
        old = __shfl(old, 0, 64);
        // Exactly one multiple of Nn in any Nn consecutive values -> exactly
        // one trigger per launch for ANY initial/poisoned counter value.
        if (((unsigned)old + 1u) % (unsigned)Nn == 0u) {
            __threadfence();            // acquire side
            double v = 1.0;
            if (lane < Nn) {
                float f = __hip_atomic_load(out + lane * Dd + occ[lane],
                                            __ATOMIC_RELAXED, __HIP_MEMORY_SCOPE_AGENT);
                v = (double)f;
            }
#pragma unroll
            for (int off = 32; off >= 1; off >>= 1)
                v *= __shfl_down(v, off, 64);
            if (lane == 0) {
                if (!isfinite(v)) v = 0.0;
                out[Nn * Dd] = (float)v;
            }
        }
    }
}

extern "C" void kernel_launch(void* const* d_in, const int* in_sizes, int n_in,
                              void* d_out, int out_size, void* d_ws, size_t ws_size,
                              hipStream_t stream) {
    const float* P = (const float*)d_in[0];      // 96x48 f32, row-major
    const int* occ = (const int*)d_in[1];        // 48 int32
    float* out = (float*)d_out;                  // 4609 f32

    slater_kernel<<<Nn, 1024, 0, stream>>>(P, occ, out, (unsigned*)d_ws);
}

// Round 5
// 100.866 us; speedup vs baseline: 1.0825x; 1.0491x over previous
//
#include <hip/hip_runtime.h>
#include <math.h>

#define Dd 96
#define Nn 48
#define LD 97
#define PTS 98   // even stride: keeps float2 (8 B) LDS loads aligned

// Fast full-precision f64 reciprocal: v_rcp_f64 + 2 Newton steps (<=1 ulp).
__device__ __forceinline__ double frcp(double x) {
    double r = __builtin_amdgcn_rcp(x);
    r = fma(fma(-x, r, 1.0), r, r);
    r = fma(fma(-x, r, 1.0), r, r);
    return r;
}

// One block per particle k (P f32; R16-verified math).
// R24: register-resident elimination. The trailing matrix lives in REGISTERS:
// wave w owns rows 6w..6w+5, lane c owns cols 2c,2c+1 (12 dbl/thread).
// Rank-6 panels align with wave ownership (panel s = wave s's rows).
//  - per step, only S = B^-1 R (owner-local compute; B via intra-wave shfl,
//    R = owner's own regs) and the 6 panel-col values per row (aBuf, broadcast
//    reads) go through LDS. T-updates are 72 register FMAs per wave per step.
//  - owner(s+1) prefactors during step s: pure intra-wave chain, ONE barrier
//    per step, no spin protocol at all.
//  - guards/emission semantics identical to R16/R23 (ev/evmask/sdead parity
//    buffers; gs handoff for remainder); merged prod epilogue kept.
__global__ __launch_bounds__(1024, 1) void slater_kernel(const float* __restrict__ P,
                                                         const int* __restrict__ occ,
                                                         float* __restrict__ out,
                                                         unsigned* __restrict__ cnt) {
    __shared__ double As[Dd * LD];      // 74,496 B (build + remainder + dump)
    __shared__ double Sbuf[2][6][Dd];   // 9,216 B: S rows for the step, by col
    __shared__ double aBuf[2][Dd][6];   // 9,216 B: panel-col values per row
    __shared__ double ev[2][6];
    __shared__ int    evmask[2], sdead[2];
    __shared__ double gs_runprod;       // guard-state handoff
    __shared__ int    gs_dead;
    __shared__ unsigned char flag[Dd];
    float* PT = (float*)As;             // scratch alias; PT reads end before As writes

    const int tid  = threadIdx.x;
    const int k    = blockIdx.x;
    const int n    = Dd - Nn + k + 1;   // xmax
    const int lane = tid & 63;
    const int wave = tid >> 6;          // 0..15
    const int xmin = (k == 0) ? 0 : occ[k - 1] + 1;

    if (tid < Dd) flag[tid] = 0;
    __syncthreads();
    if (tid < k) flag[occ[tid]] = 1;
    for (int e = tid; e < Dd * Nn; e += 1024) {      // PT[t][c] = P[c][t]
        int c = e / Nn, t = e - (e / Nn) * Nn;
        PT[t * PTS + c] = P[e];
    }
    __syncthreads();

    // A = I*(1-flag) - P P^T is SYMMETRIC: upper-tri 2x2 tiles (1176), mirror
    // writes for the lower half. 1024 threads -> 2 partial iterations.
    double Areg[8]; int trs[2], tcs[2];
#pragma unroll
    for (int it = 0; it < 2; ++it) {
        int tau = tid + 1024 * it;
        double s00 = 0.0, s01 = 0.0, s10 = 0.0, s11 = 0.0;
        int tr = 0, tc = 0;
        if (tau < 1176) {
            tr = (int)((97.0 - sqrt(9409.0 - 8.0 * (double)tau)) * 0.5);
            while ((tr * (97 - tr)) / 2 > tau) --tr;            // off(tr) <= tau
            while (((tr + 1) * (96 - tr)) / 2 <= tau) ++tr;     // off(tr+1) > tau
            tc = tr + (tau - (tr * (97 - tr)) / 2);
            int r0 = 2 * tr, c0 = 2 * tc;
            if (r0 < n && c0 < n) {
                for (int t = 0; t < Nn; ++t) {
                    const float* row = PT + t * PTS;
                    float2 pr = *(const float2*)(row + r0);
                    float2 pc = *(const float2*)(row + c0);
                    s00 -= (double)pr.x * (double)pc.x; s01 -= (double)pr.x * (double)pc.y;
                    s10 -= (double)pr.y * (double)pc.x; s11 -= (double)pr.y * (double)pc.y;
                }
            }
        }
        trs[it] = tr; tcs[it] = tc;
        Areg[it * 4 + 0] = s00; Areg[it * 4 + 1] = s01;
        Areg[it * 4 + 2] = s10; Areg[it * 4 + 3] = s11;
    }
    __syncthreads();                    // all PT reads done before As overwrite
#pragma unroll
    for (int it = 0; it < 2; ++it) {
        int tau = tid + 1024 * it;
        if (tau < 1176) {
            int tr = trs[it], tc = tcs[it];
            int r0 = 2 * tr, c0 = 2 * tc;
            if (r0 < n && c0 < n) {
                bool r1 = (r0 + 1 < n), c1 = (c0 + 1 < n);
                double d0 = flag[r0] ? 0.0 : 1.0;
                double d1 = flag[r0 + 1] ? 0.0 : 1.0;
                As[r0 * LD + c0] = Areg[it * 4 + 0] + ((r0 == c0) ? d0 : 0.0);
                if (c1)       As[r0 * LD + c0 + 1]       = Areg[it * 4 + 1];
                if (r1)       As[(r0 + 1) * LD + c0]     = Areg[it * 4 + 2];
                if (r1 && c1) As[(r0 + 1) * LD + c0 + 1] = Areg[it * 4 + 3] + ((r0 == c0) ? d1 : 0.0);
                if (tr != tc) {  // mirror (transpose) write
                    As[c0 * LD + r0] = Areg[it * 4 + 0];
                    if (c1)       As[(c0 + 1) * LD + r0]     = Areg[it * 4 + 1];
                    if (r1)       As[c0 * LD + r0 + 1]       = Areg[it * 4 + 2];
                    if (r1 && c1) As[(c0 + 1) * LD + r0 + 1] = Areg[it * 4 + 3];
                }
            }
        }
    }
    __syncthreads();

    double myprob = 0.0;
    double rr[6][2];                    // my 6 rows x my 2 cols

    // Owner-wave routine: gather panel B (cols jb..jb+5 of my rows) via
    // intra-wave shuffles, 6x6 in-place LU, guard chain (lane 0, continuing
    // from (grun,gdead)), S = B^-1 R for my 2 cols (R = my own regs).
    // Executed by ALL lanes of the owner wave (redundant factor; shfl needs
    // full wave). Writes Sbuf[p] (zeros for cols < jb+6), ev/evmask/sdead/gs.
    auto prefactor = [&](int jb, int p, double grun, int gdead) {
        double Bd[6][6], rp[6];
#pragma unroll
        for (int u = 0; u < 6; ++u) {
#pragma unroll
            for (int r = 0; r < 6; ++r)
                Bd[u][r] = __shfl((r & 1) ? rr[u][1] : rr[u][0], (jb + r) >> 1, 64);
        }
#pragma unroll
        for (int cc = 0; cc < 6; ++cc) {
            rp[cc] = frcp(Bd[cc][cc]);
#pragma unroll
            for (int i = cc + 1; i < 6; ++i) {
                double m = Bd[i][cc] * rp[cc];
                Bd[i][cc] = m;
#pragma unroll
                for (int r = cc + 1; r < 6; ++r) Bd[i][r] -= m * Bd[cc][r];
            }
        }
        if (lane == 0) {                // guards: exact R16/R23 semantics
            int msk = 0; double evv[6];
#pragma unroll
            for (int q = 0; q < 6; ++q) {
                evv[q] = 0.0;
                if (!gdead) {
                    int jj = jb + q;
                    double pv = Bd[q][q];
                    double ap = fabs(pv);
                    if (jj >= xmin) {
                        evv[q] = grun * (1.0 - pv);    // emit BEFORE any cut
                        msk |= (1 << q);
                        double nr = grun * pv;
                        if (!(ap > 1e-7) || !(ap < 8.0) || !(fabs(nr) > 1e-8)) gdead = 1;
                        else grun = nr;
                    } else {
                        if (!(ap > 1e-12) || !(ap < 8.0)) gdead = 1;
                    }
                }
            }
#pragma unroll
            for (int q = 0; q < 6; ++q) ev[p][q] = evv[q];
            evmask[p] = msk; sdead[p] = gdead;
            gs_runprod = grun; gs_dead = gdead;
        }
        if (lane < 48) {
            const bool live = (2 * lane >= jb + 6);   // both my cols share parity
#pragma unroll
            for (int sl = 0; sl < 2; ++sl) {
                double y0 = rr[0][sl];
                double y1 = rr[1][sl] - Bd[1][0] * y0;
                double y2 = rr[2][sl] - Bd[2][0] * y0 - Bd[2][1] * y1;
                double y3 = rr[3][sl] - Bd[3][0] * y0 - Bd[3][1] * y1 - Bd[3][2] * y2;
                double y4 = rr[4][sl] - Bd[4][0] * y0 - Bd[4][1] * y1 - Bd[4][2] * y2 - Bd[4][3] * y3;
                double y5 = rr[5][sl] - Bd[5][0] * y0 - Bd[5][1] * y1 - Bd[5][2] * y2 - Bd[5][3] * y3 - Bd[5][4] * y4;
                double s5 = y5 * rp[5];
                double s4 = (y4 - Bd[4][5] * s5) * rp[4];
                double s3 = (y3 - Bd[3][4] * s4 - Bd[3][5] * s5) * rp[3];
                double s2 = (y2 - Bd[2][3] * s3 - Bd[2][4] * s4 - Bd[2][5] * s5) * rp[2];
                double s1 = (y1 - Bd[1][2] * s2 - Bd[1][3] * s3 - Bd[1][4] * s4 - Bd[1][5] * s5) * rp[1];
                double s0 = (y0 - Bd[0][1] * s1 - Bd[0][2] * s2 - Bd[0][3] * s3 - Bd[0][4] * s4 - Bd[0][5] * s5) * rp[0];
                Sbuf[p][0][2 * lane + sl] = live ? s0 : 0.0;
                Sbuf[p][1][2 * lane + sl] = live ? s1 : 0.0;
                Sbuf[p][2][2 * lane + sl] = live ? s2 : 0.0;
                Sbuf[p][3][2 * lane + sl] = live ? s3 : 0.0;
                Sbuf[p][4][2 * lane + sl] = live ? s4 : 0.0;
                Sbuf[p][5][2 * lane + sl] = live ? s5 : 0.0;
            }
        }
    };

    // ---- load my rows into registers ----
#pragma unroll
    for (int u = 0; u < 6; ++u) {
        if (lane < 48) {
            rr[u][0] = As[(6 * wave + u) * LD + 2 * lane];
            rr[u][1] = As[(6 * wave + u) * LD + 2 * lane + 1];
        } else { rr[u][0] = 0.0; rr[u][1] = 0.0; }
    }
    // initial aBuf[0]: panel-0 cols (0..5) of all trailing rows (waves >= 1)
    if (wave >= 1 && lane < 3) {
#pragma unroll
        for (int u = 0; u < 6; ++u) {
            aBuf[0][6 * wave + u][2 * lane]     = rr[u][0];
            aBuf[0][6 * wave + u][2 * lane + 1] = rr[u][1];
        }
    }
    if (wave == 0) prefactor(0, 0, 1.0, 0);
    __syncthreads();

    // ---- rank-6 super-steps, matrix in registers ----
    int j = 0, s = 0;
    for (; j + 6 <= n - 1; j += 6, ++s) {
        const int par = s & 1;
        if (tid >= j && tid < j + 6) {           // emission (precomputed)
            int q = tid - j;
            if ((evmask[par] >> q) & 1) myprob = ev[par][q];
        }
        if (sdead[par]) break;
        const bool nexts = (j + 12 <= n - 1);    // next super-step exists

        if (wave >= s + 1) {
            if (lane < 48) {
                double S0[6], S1[6];
#pragma unroll
                for (int r = 0; r < 6; ++r) {
                    double2 sv = *(const double2*)&Sbuf[par][r][2 * lane];
                    S0[r] = sv.x; S1[r] = sv.y;
                }
#pragma unroll
                for (int u = 0; u < 6; ++u) {    // 72 register FMAs
                    const double* ab = &aBuf[par][6 * wave + u][0];
                    double2 q0 = *(const double2*)(ab + 0);
                    double2 q1 = *(const double2*)(ab + 2);
                    double2 q2 = *(const double2*)(ab + 4);
                    rr[u][0] -= q0.x * S0[0] + q0.y * S0[1] + q1.x * S0[2]
                              + q1.y * S0[3] + q2.x * S0[4] + q2.y * S0[5];
                    rr[u][1] -= q0.x * S1[0] + q0.y * S1[1] + q1.x * S1[2]
                              + q1.y * S1[3] + q2.x * S1[4] + q2.y * S1[5];
                }
                // publish next panel's a-cols (j+6..j+11) for rows that will
                // still be trailing at step s+1 (waves >= s+2)
                if (nexts && wave >= s + 2) {
                    int d = lane - 3 * (s + 1);
                    if (d >= 0 && d < 3) {
#pragma unroll
                        for (int u = 0; u < 6; ++u) {
                            aBuf[par ^ 1][6 * wave + u][2 * d]     = rr[u][0];
                            aBuf[par ^ 1][6 * wave + u][2 * d + 1] = rr[u][1];
                        }
                    }
                }
            }
            // owner of step s+1: everything intra-wave (B via shfl, R = regs)
            if (nexts && wave == s + 1)
                prefactor(j + 6, par ^ 1, gs_runprod, gs_dead);
        }
        __syncthreads();
    }

    // ---- dump registers back to As for remainder/output ----
    if (lane < 48) {
#pragma unroll
        for (int u = 0; u < 6; ++u) {
            As[(6 * wave + u) * LD + 2 * lane]     = rr[u][0];
            As[(6 * wave + u) * LD + 2 * lane + 1] = rr[u][1];
        }
    }
    __syncthreads();

    double runprod = gs_runprod;
    bool   dead    = (gs_dead != 0);

    // ---- remainder single steps (R16-proven body, 16-wave stride) ----
    for (; !dead && j < n - 1; ++j) {
        double pivot = As[j * LD + j];
        {
            double ap = fabs(pivot);
            if (j >= xmin) {
                if (tid == j) myprob = runprod * (1.0 - pivot);
                double nr = runprod * pivot;
                if (!(ap > 1e-7) || !(ap < 8.0) || !(fabs(nr) > 1e-8)) dead = true;
                else runprod = nr;
            } else {
                if (!(ap > 1e-12) || !(ap < 8.0)) dead = true;
            }
        }
        if (dead) break;
        double rp = frcp(pivot);
        int t = n - 1 - j;
        double r0 = (lane < t)      ? As[j * LD + j + 1 + lane]  : 0.0;
        double r1 = (lane + 64 < t) ? As[j * LD + j + 65 + lane] : 0.0;
        for (int i = j + 1 + wave; i < n; i += 16) {
            double mult = As[i * LD + j] * rp;
            if (lane < t)      As[i * LD + j + 1 + lane]  -= mult * r0;
            if (lane + 64 < t) As[i * LD + j + 65 + lane] -= mult * r1;
        }
        __syncthreads();
    }
    if (!dead && tid == n - 1) {        // x = xmax-1: remaining mass
        double pl = As[(n - 1) * LD + (n - 1)];
        myprob = runprod * (1.0 - pl);
    }

    if (tid < Dd) {
        double p = myprob;
        if (!isfinite(p)) p = 0.0;
        if (!(fabs(p) > 1e-15)) p = 0.0;   // reference's flush
        p = fmin(fmax(p, 0.0), 1.0);       // junk-proof projection
        out[k * Dd + tid] = (float)p;
    }

    // ---- merged prob_sample: last-arriving block does the product ----
    __threadfence();
    __syncthreads();
    if (wave == 0) {
        int old = 0;
        if (lane == 0)
            old = (int)__hip_atomic_fetch_add(cnt, 1u, __ATOMIC_ACQ_REL,
                                              __HIP_MEMORY_SCOPE_AGENT);
        old = __shfl(old, 0, 64);
        // Exactly one multiple of Nn in any Nn consecutive values -> exactly
        // one trigger per launch for ANY initial/poisoned counter value.
        if (((unsigned)old + 1u) % (unsigned)Nn == 0u) {
            __threadfence();            // acquire side
            double v = 1.0;
            if (lane < Nn) {
                float f = __hip_atomic_load(out + lane * Dd + occ[lane],
                                            __ATOMIC_RELAXED, __HIP_MEMORY_SCOPE_AGENT);
                v = (double)f;
            }
#pragma unroll
            for (int off = 32; off >= 1; off >>= 1)
                v *= __shfl_down(v, off, 64);
            if (lane == 0) {
                if (!isfinite(v)) v = 0.0;
                out[Nn * Dd] = (float)v;
            }
        }
    }
}

extern "C" void kernel_launch(void* const* d_in, const int* in_sizes, int n_in,
                              void* d_out, int out_size, void* d_ws, size_t ws_size,
                              hipStream_t stream) {
    const float* P = (const float*)d_in[0];      // 96x48 f32, row-major
    const int* occ = (const int*)d_in[1];        // 48 int32
    float* out = (float*)d_out;                  // 4609 f32

    slater_kernel<<<Nn, 1024, 0, stream>>>(P, occ, out, (unsigned*)d_ws);
}